// Round 5
// baseline (824.849 us; speedup 1.0000x reference)
//
#include <hip/hip_runtime.h>

// Problem dims
#define B_    8
#define N_    1024
#define DIN   512
#define H_    8
#define DH    64
#define DQKV  6144   // 2*DQ + 2*DQ + DV = 512+512+512+512+4096
#define DEXP  2048
#define DTIME 256

typedef __attribute__((ext_vector_type(8))) short s16x8;   // 8 bf16 (MFMA A/B frag)
typedef __attribute__((ext_vector_type(4))) short s16x4;
typedef __attribute__((ext_vector_type(4))) float f32x4;   // MFMA C/D frag

__device__ __forceinline__ unsigned short f2bf(float f) {
  unsigned int u = __float_as_uint(f);
  u = (u + 0x7fffu + ((u >> 16) & 1u)) >> 16;   // RNE
  return (unsigned short)u;
}

__device__ __forceinline__ void gload_lds16(const unsigned short* g, unsigned short* l) {
  __builtin_amdgcn_global_load_lds(
      (const __attribute__((address_space(1))) unsigned int*)(g),
      (__attribute__((address_space(3))) unsigned int*)(l), 16, 0, 0);
}

// ---------------- LayerNorm (D=512), optional per-batch additive row, bf16 out ----
__global__ __launch_bounds__(256) void ln_k(
    const float* __restrict__ x, const float* __restrict__ add,
    const float* __restrict__ g, const float* __restrict__ bb,
    unsigned short* __restrict__ out)
{
  int row = blockIdx.x;
  int tid = threadIdx.x;
  const float* xr = x + (size_t)row * DIN;
  float v0 = xr[tid], v1 = xr[tid + 256];
  if (add) {
    const float* ar = add + (size_t)(row >> 10) * DIN;   // row/1024 = batch idx
    v0 += ar[tid]; v1 += ar[tid + 256];
  }
  float s = v0 + v1, sq = v0 * v0 + v1 * v1;
  #pragma unroll
  for (int m = 1; m < 64; m <<= 1) { s += __shfl_xor(s, m, 64); sq += __shfl_xor(sq, m, 64); }
  __shared__ float red[8];
  int w = tid >> 6;
  if ((tid & 63) == 0) { red[w] = s; red[4 + w] = sq; }
  __syncthreads();
  s  = red[0] + red[1] + red[2] + red[3];
  sq = red[4] + red[5] + red[6] + red[7];
  float mean = s * (1.0f / DIN);
  float var  = sq * (1.0f / DIN) - mean * mean;
  float rs = rsqrtf(var + 1e-5f);
  unsigned short* orow = out + (size_t)row * DIN;
  orow[tid]       = f2bf((v0 - mean) * rs * g[tid]       + bb[tid]);
  orow[tid + 256] = f2bf((v1 - mean) * rs * g[tid + 256] + bb[tid + 256]);
}

// ---------------- f32 [R][C] -> bf16 [C][R] transpose (weights) ------------------
__global__ __launch_bounds__(256) void wtrans_k(
    const float* __restrict__ in, unsigned short* __restrict__ out, int R, int C)
{
  __shared__ float tile[32][33];
  int tx = threadIdx.x & 31, ty = threadIdx.x >> 5;
  int c0 = blockIdx.x * 32, r0 = blockIdx.y * 32;
  #pragma unroll
  for (int k = 0; k < 4; ++k)
    tile[ty + k * 8][tx] = in[(size_t)(r0 + ty + k * 8) * C + c0 + tx];
  __syncthreads();
  #pragma unroll
  for (int k = 0; k < 4; ++k)
    out[(size_t)(c0 + ty + k * 8) * R + r0 + tx] = f2bf(tile[tx][ty + k * 8]);
}

// ---------------- time MLP: tp[b][512] = swish(t@Wt1+bt1)@Wt2+bt2 ---------------
__global__ __launch_bounds__(256) void time_k(
    const float* __restrict__ t, const float* __restrict__ Wt1, const float* __restrict__ bt1,
    const float* __restrict__ Wt2, const float* __restrict__ bt2, float* __restrict__ tp)
{
  int b = blockIdx.x, tid = threadIdx.x;
  __shared__ float tl[256], hl[256];
  tl[tid] = t[(size_t)b * 256 + tid];
  __syncthreads();
  float a = bt1[tid];
  for (int k = 0; k < 256; ++k) a += tl[k] * Wt1[(size_t)k * 256 + tid];
  hl[tid] = a / (1.0f + __expf(-a));
  __syncthreads();
  for (int j = tid; j < 512; j += 256) {
    float a2 = bt2[j];
    for (int k = 0; k < 256; ++k) a2 += hl[k] * Wt2[(size_t)k * 512 + j];
    tp[(size_t)b * 512 + j] = a2;
  }
}

// ---------------- bf16 MFMA GEMM: C = epi(A @ Bt^T + bias [+res]) ---------------
// A [M][lda] bf16 ; Bt [N][K] bf16 ; 128x128 tile, BK=32, 4 waves (2x2 of 64x64)
// global_load_lds width-16 staging into linear LDS (m97 structure).
// EPI: 0 = bias -> bf16 ; 1 = bias+swish -> bf16 ; 2 = bias+res(f32) -> f32
//      3 = bias -> bf16, but V-columns (n0>=2048) written transposed into vtout
template<int EPI>
__global__ __launch_bounds__(256) void gemm_bt(
    const unsigned short* __restrict__ A, int lda,
    const unsigned short* __restrict__ Bt,
    const float* __restrict__ bias, const float* __restrict__ res,
    void* __restrict__ C, int ldc, int N, int K,
    unsigned short* __restrict__ vtout)
{
  __shared__ __attribute__((aligned(16))) unsigned short As[128 * 32];
  __shared__ __attribute__((aligned(16))) unsigned short Bs[128 * 32];
  int tid = threadIdx.x;
  int m0 = blockIdx.y * 128, n0 = blockIdx.x * 128;
  int lane = tid & 63, wid = tid >> 6;
  int wr = wid >> 1, wc = wid & 1;
  int lr = lane & 15, lg = lane >> 4, lk = lg * 8;
  f32x4 zero = {0.f, 0.f, 0.f, 0.f};
  f32x4 acc[4][4];
  #pragma unroll
  for (int i = 0; i < 4; ++i)
    #pragma unroll
    for (int j = 0; j < 4; ++j) acc[i][j] = zero;
  // staging: wave wid covers rows wid*16..wid*16+15 of each 64-row half
  int srow = wid * 16 + (lane >> 2);
  int schunk = (lane & 3) * 8;
  const unsigned short* gA0 = A  + (size_t)(m0 + srow) * lda + schunk;
  const unsigned short* gA1 = gA0 + (size_t)64 * lda;
  const unsigned short* gB0 = Bt + (size_t)(n0 + srow) * K + schunk;
  const unsigned short* gB1 = gB0 + (size_t)64 * K;
  unsigned short* lA0 = As + wid * 512;          // wave-uniform bases
  unsigned short* lA1 = As + 2048 + wid * 512;
  unsigned short* lB0 = Bs + wid * 512;
  unsigned short* lB1 = Bs + 2048 + wid * 512;
  for (int kt = 0; kt < K; kt += 32) {
    gload_lds16(gA0 + kt, lA0);
    gload_lds16(gA1 + kt, lA1);
    gload_lds16(gB0 + kt, lB0);
    gload_lds16(gB1 + kt, lB1);
    __syncthreads();
    s16x8 af[4], bf[4];
    #pragma unroll
    for (int mf = 0; mf < 4; ++mf) af[mf] = *(const s16x8*)&As[(wr * 64 + mf * 16 + lr) * 32 + lk];
    #pragma unroll
    for (int nf = 0; nf < 4; ++nf) bf[nf] = *(const s16x8*)&Bs[(wc * 64 + nf * 16 + lr) * 32 + lk];
    #pragma unroll
    for (int mf = 0; mf < 4; ++mf)
      #pragma unroll
      for (int nf = 0; nf < 4; ++nf)
        acc[mf][nf] = __builtin_amdgcn_mfma_f32_16x16x32_bf16(af[mf], bf[nf], acc[mf][nf], 0, 0, 0);
    __syncthreads();
  }
  if (EPI == 3 && n0 >= 2048) {
    // V columns -> vt [bh][c(512)][kv(1024)], packed 8B stores (4 consecutive kv)
    #pragma unroll
    for (int mf = 0; mf < 4; ++mf) {
      int row = m0 + wr * 64 + mf * 16 + lg * 4;
      int bb = row >> 10, nn = row & 1023;
      #pragma unroll
      for (int nf = 0; nf < 4; ++nf) {
        int col = n0 + wc * 64 + nf * 16 + lr;
        float bcol = bias[col];
        int hc = col - 2048;
        int hh = hc >> 9, cc = hc & 511;
        unsigned short pk[4];
        #pragma unroll
        for (int r = 0; r < 4; ++r) pk[r] = f2bf(acc[mf][nf][r] + bcol);
        *(s16x4*)(vtout + ((size_t)((bb * 8 + hh) * 512 + cc)) * 1024 + nn) = *(const s16x4*)pk;
      }
    }
    return;
  }
  #pragma unroll
  for (int mf = 0; mf < 4; ++mf)
    #pragma unroll
    for (int nf = 0; nf < 4; ++nf) {
      int col = n0 + wc * 64 + nf * 16 + lr;
      float bcol = bias[col];
      #pragma unroll
      for (int r = 0; r < 4; ++r) {
        int row = m0 + wr * 64 + mf * 16 + lg * 4 + r;
        float v = acc[mf][nf][r] + bcol;
        if (EPI == 1) v = v / (1.0f + __expf(-v));            // swish
        if (EPI == 2) {
          v += res[(size_t)row * N + col];
          ((float*)C)[(size_t)row * ldc + col] = v;
        } else {
          ((unsigned short*)C)[(size_t)row * ldc + col] = f2bf(v);
        }
      }
    }
}

// ---------------- attention pass A: exact row stats (m,l) for both softmaxes ----
// block = (b,h,qtile of 64 rows), 4 waves; wave w owns rows w*16..w*16+15
// XCD-swizzled so same-bh blocks colocate (K reads L2-resident per XCD).
__global__ __launch_bounds__(256) void attn_stats_k(
    const unsigned short* __restrict__ qkv,
    float* __restrict__ stm1, float* __restrict__ stl1,
    float* __restrict__ stm2, float* __restrict__ stl2)
{
  const float scale = 0.125f;
  int w0 = blockIdx.x;
  int bx = (w0 & 7) * 128 + (w0 >> 3);        // 1024 blocks, bijective
  int bh = bx >> 4, qt = bx & 15;
  int b = bh >> 3, h = bh & 7;
  int tid = threadIdx.x;
  int lane = tid & 63, w = tid >> 6;
  int lr = lane & 15, lg = lane >> 4, lk = lg * 8;
  size_t qrowoff = (size_t)(b * N_ + qt * 64 + w * 16 + lr) * DQKV;
  int qc1 = h * 64, qc2 = 512 + h * 64, kc1 = 1024 + h * 64, kc2 = 1536 + h * 64;
  s16x8 q1f[2], q2f[2];
  #pragma unroll
  for (int kf = 0; kf < 2; ++kf) {
    q1f[kf] = *(const s16x8*)(qkv + qrowoff + qc1 + kf * 32 + lk);
    q2f[kf] = *(const s16x8*)(qkv + qrowoff + qc2 + kf * 32 + lk);
  }
  float m1p[4], l1p[4], m2p[4], l2p[4];
  #pragma unroll
  for (int r = 0; r < 4; ++r) { m1p[r] = -1e30f; l1p[r] = 0.f; m2p[r] = -1e30f; l2p[r] = 0.f; }
  f32x4 zero = {0.f, 0.f, 0.f, 0.f};
  for (int kt = 0; kt < 16; ++kt) {
    f32x4 s1[4], s2[4];
    #pragma unroll
    for (int nf = 0; nf < 4; ++nf) {
      s1[nf] = zero; s2[nf] = zero;
      size_t krowoff = (size_t)(b * N_ + kt * 64 + nf * 16 + lr) * DQKV;
      #pragma unroll
      for (int kf = 0; kf < 2; ++kf) {
        s16x8 k1f = *(const s16x8*)(qkv + krowoff + kc1 + kf * 32 + lk);
        s16x8 k2f = *(const s16x8*)(qkv + krowoff + kc2 + kf * 32 + lk);
        s1[nf] = __builtin_amdgcn_mfma_f32_16x16x32_bf16(q1f[kf], k1f, s1[nf], 0, 0, 0);
        s2[nf] = __builtin_amdgcn_mfma_f32_16x16x32_bf16(q2f[kf], k2f, s2[nf], 0, 0, 0);
      }
    }
    #pragma unroll
    for (int r = 0; r < 4; ++r) {
      {
        float v0 = s1[0][r] * scale, v1 = s1[1][r] * scale, v2 = s1[2][r] * scale, v3 = s1[3][r] * scale;
        float nm = fmaxf(m1p[r], fmaxf(fmaxf(v0, v1), fmaxf(v2, v3)));
        l1p[r] = l1p[r] * __expf(m1p[r] - nm)
               + __expf(v0 - nm) + __expf(v1 - nm) + __expf(v2 - nm) + __expf(v3 - nm);
        m1p[r] = nm;
      }
      {
        float v0 = s2[0][r] * scale, v1 = s2[1][r] * scale, v2 = s2[2][r] * scale, v3 = s2[3][r] * scale;
        float nm = fmaxf(m2p[r], fmaxf(fmaxf(v0, v1), fmaxf(v2, v3)));
        l2p[r] = l2p[r] * __expf(m2p[r] - nm)
               + __expf(v0 - nm) + __expf(v1 - nm) + __expf(v2 - nm) + __expf(v3 - nm);
        m2p[r] = nm;
      }
    }
  }
  #pragma unroll
  for (int r = 0; r < 4; ++r) {
    #pragma unroll
    for (int m = 1; m < 16; m <<= 1) {
      float om = __shfl_xor(m1p[r], m, 64), ol = __shfl_xor(l1p[r], m, 64);
      float nm = fmaxf(m1p[r], om);
      l1p[r] = l1p[r] * __expf(m1p[r] - nm) + ol * __expf(om - nm);
      m1p[r] = nm;
      om = __shfl_xor(m2p[r], m, 64); ol = __shfl_xor(l2p[r], m, 64);
      nm = fmaxf(m2p[r], om);
      l2p[r] = l2p[r] * __expf(m2p[r] - nm) + ol * __expf(om - nm);
      m2p[r] = nm;
    }
  }
  if (lr == 0) {
    #pragma unroll
    for (int r = 0; r < 4; ++r) {
      int idx = bh * N_ + qt * 64 + w * 16 + lg * 4 + r;
      stm1[idx] = m1p[r]; stl1[idx] = l1p[r]; stm2[idx] = m2p[r]; stl2[idx] = l2p[r];
    }
  }
}

// ---------------- attention pass B: P = e1/l1 - lam*e2/l2 ; O = P @ V -----------
// block = (b,h,qtile of 32 rows), 8 waves, XCD-swizzled for V/K L2 locality.
// K(it+1) reg-prefetch issued at iteration top (latency hides under QK+softmax).
// Plain __syncthreads() barriers (safe variant).
__global__ __launch_bounds__(512) void attn_pv_k(
    const unsigned short* __restrict__ qkv, const unsigned short* __restrict__ vt,
    const float* __restrict__ stm1, const float* __restrict__ stl1,
    const float* __restrict__ stm2, const float* __restrict__ stl2,
    const float* __restrict__ lamp, unsigned short* __restrict__ aout /* = qkv+2048 */)
{
  const float scale = 0.125f;
  __shared__ __attribute__((aligned(16))) unsigned short P[2][32][132]; // 264B stride: 2-way banks
  int w0 = blockIdx.x;
  int bx = (w0 & 7) * 256 + (w0 >> 3);        // 2048 blocks, bijective XCD swizzle
  int bh = bx >> 5, qt = bx & 31;
  int b = bh >> 3, h = bh & 7;
  int tid = threadIdx.x;
  int lane = tid & 63, w = tid >> 6;
  int lr = lane & 15, lg = lane >> 4, lk = lg * 8;
  float lam = *lamp;
  // stats for the 8 q-rows this lane's acc registers map to (q = mf*16+lg*4+r)
  float m1v[2][4], r1v[2][4], m2v[2][4], r2v[2][4];
  #pragma unroll
  for (int mf = 0; mf < 2; ++mf)
    #pragma unroll
    for (int r = 0; r < 4; ++r) {
      int qg = bh * N_ + qt * 32 + mf * 16 + lg * 4 + r;
      m1v[mf][r] = stm1[qg]; r1v[mf][r] = 1.f / stl1[qg];
      m2v[mf][r] = stm2[qg]; r2v[mf][r] = lam / stl2[qg];
    }
  int qc1 = h * 64, qc2 = 512 + h * 64, kc1 = 1024 + h * 64, kc2 = 1536 + h * 64;
  s16x8 q1f[2][2], q2f[2][2];
  #pragma unroll
  for (int mf = 0; mf < 2; ++mf)
    #pragma unroll
    for (int kf = 0; kf < 2; ++kf) {
      size_t ro = (size_t)(b * N_ + qt * 32 + mf * 16 + lr) * DQKV;
      q1f[mf][kf] = *(const s16x8*)(qkv + ro + qc1 + kf * 32 + lk);
      q2f[mf][kf] = *(const s16x8*)(qkv + ro + qc2 + kf * 32 + lk);
    }
  f32x4 zero = {0.f, 0.f, 0.f, 0.f};
  f32x4 O[2][4];
  #pragma unroll
  for (int mf = 0; mf < 2; ++mf)
    #pragma unroll
    for (int nf = 0; nf < 4; ++nf) O[mf][nf] = zero;
  // prologue: K(0) into current regs
  s16x8 k1c[2], k2c[2];
  {
    size_t kro = (size_t)(b * N_ + w * 16 + lr) * DQKV;
    #pragma unroll
    for (int kf = 0; kf < 2; ++kf) {
      k1c[kf] = *(const s16x8*)(qkv + kro + kc1 + kf * 32 + lk);
      k2c[kf] = *(const s16x8*)(qkv + kro + kc2 + kf * 32 + lk);
    }
  }
  for (int it = 0; it < 8; ++it) {
    int pb = it & 1;
    // prefetch K(it+1): issued now, consumed next iteration
    s16x8 k1n[2], k2n[2];
    if (it < 7) {
      size_t kro = (size_t)(b * N_ + (it + 1) * 128 + w * 16 + lr) * DQKV;
      #pragma unroll
      for (int kf = 0; kf < 2; ++kf) {
        k1n[kf] = *(const s16x8*)(qkv + kro + kc1 + kf * 32 + lk);
        k2n[kf] = *(const s16x8*)(qkv + kro + kc2 + kf * 32 + lk);
      }
    }
    // QK^T for this iteration's 128-kv chunk (wave w owns kv w*16..w*16+15)
    f32x4 s1a[2], s2a[2];
    s1a[0] = zero; s1a[1] = zero; s2a[0] = zero; s2a[1] = zero;
    #pragma unroll
    for (int kf = 0; kf < 2; ++kf)
      #pragma unroll
      for (int mf = 0; mf < 2; ++mf) {
        s1a[mf] = __builtin_amdgcn_mfma_f32_16x16x32_bf16(q1f[mf][kf], k1c[kf], s1a[mf], 0, 0, 0);
        s2a[mf] = __builtin_amdgcn_mfma_f32_16x16x32_bf16(q2f[mf][kf], k2c[kf], s2a[mf], 0, 0, 0);
      }
    // P in registers via preloaded exact stats, write bf16 to LDS
    #pragma unroll
    for (int mf = 0; mf < 2; ++mf)
      #pragma unroll
      for (int r = 0; r < 4; ++r) {
        float p = __expf(s1a[mf][r] * scale - m1v[mf][r]) * r1v[mf][r]
                - __expf(s2a[mf][r] * scale - m2v[mf][r]) * r2v[mf][r];
        P[pb][mf * 16 + lg * 4 + r][w * 16 + lr] = f2bf(p);
      }
    __syncthreads();
    // PV: wave w multiplies full P tile by its 64 v-cols
    #pragma unroll
    for (int kf = 0; kf < 4; ++kf) {
      s16x8 pf0 = *(const s16x8*)&P[pb][lr][kf * 32 + lk];
      s16x8 pf1 = *(const s16x8*)&P[pb][16 + lr][kf * 32 + lk];
      #pragma unroll
      for (int nf = 0; nf < 4; ++nf) {
        s16x8 vf = *(const s16x8*)(vt + (size_t)(bh * 512 + w * 64 + nf * 16 + lr) * N_
                                   + it * 128 + kf * 32 + lk);
        O[0][nf] = __builtin_amdgcn_mfma_f32_16x16x32_bf16(pf0, vf, O[0][nf], 0, 0, 0);
        O[1][nf] = __builtin_amdgcn_mfma_f32_16x16x32_bf16(pf1, vf, O[1][nf], 0, 0, 0);
      }
    }
    if (it < 7) {
      #pragma unroll
      for (int kf = 0; kf < 2; ++kf) { k1c[kf] = k1n[kf]; k2c[kf] = k2n[kf]; }
    }
  }
  #pragma unroll
  for (int mf = 0; mf < 2; ++mf)
    #pragma unroll
    for (int nf = 0; nf < 4; ++nf) {
      int col = h * 512 + w * 64 + nf * 16 + lr;
      #pragma unroll
      for (int r = 0; r < 4; ++r) {
        int row = b * N_ + qt * 32 + mf * 16 + lg * 4 + r;
        aout[(size_t)row * DQKV + col] = f2bf(O[mf][nf][r]);
      }
    }
}

// ---------------------------------- launcher ------------------------------------
extern "C" void kernel_launch(void* const* d_in, const int* in_sizes, int n_in,
                              void* d_out, int out_size, void* d_ws, size_t ws_size,
                              hipStream_t stream) {
  const float* x    = (const float*)d_in[0];
  const float* t    = (const float*)d_in[1];
  const float* ln1g = (const float*)d_in[2];
  const float* ln1b = (const float*)d_in[3];
  const float* Wqkv = (const float*)d_in[4];
  const float* bqkv = (const float*)d_in[5];
  const float* lam  = (const float*)d_in[6];
  const float* Wm   = (const float*)d_in[7];
  const float* bm   = (const float*)d_in[8];
  const float* Wt1  = (const float*)d_in[9];
  const float* bt1  = (const float*)d_in[10];
  const float* Wt2  = (const float*)d_in[11];
  const float* bt2  = (const float*)d_in[12];
  const float* lnfg = (const float*)d_in[13];
  const float* lnfb = (const float*)d_in[14];
  const float* Wf1  = (const float*)d_in[15];
  const float* bf1  = (const float*)d_in[16];
  const float* Wf2  = (const float*)d_in[17];
  const float* bf2  = (const float*)d_in[18];
  float* out = (float*)d_out;
  char* ws = (char*)d_ws;

  // workspace layout (bytes), ~209 MB total
  unsigned short* qkv   = (unsigned short*)(ws);                  // [8192][6144] bf16 (100.7MB)
  unsigned short* vt    = (unsigned short*)(ws + 100663296ull);   // [64][512][1024] bf16 (67MB)
  float*          x2    = (float*)(ws + 167772160ull);            // [8192][512] f32 (16.8MB)
  unsigned short* xn    = (unsigned short*)(ws + 184549376ull);   // [8192][512] bf16 (xn, then h)
  float*          stm1  = (float*)(ws + 192937984ull);            // 4 x 65536 f32 stats
  float*          stl1  = stm1 + 65536;
  float*          stm2  = stm1 + 131072;
  float*          stl2  = stm1 + 196608;
  unsigned short* WqkvT = (unsigned short*)(ws + 193986560ull);   // [6144][512]
  unsigned short* WmT   = (unsigned short*)(ws + 200278016ull);   // [512][4096]
  unsigned short* Wf1T  = (unsigned short*)(ws + 204472320ull);   // [2048][512]
  unsigned short* Wf2T  = (unsigned short*)(ws + 206569472ull);   // [512][2048]
  float*          tp    = (float*)(ws + 208666624ull);            // [8][512]
  unsigned short* ff1s  = qkv;          // alias: qkv dead after attention
  unsigned short* aout  = qkv + 2048;   // alias: attention out over dead V region

  // weights -> bf16 transposed [N][K]
  wtrans_k<<<dim3(DQKV / 32, DIN / 32),  256, 0, stream>>>(Wqkv, WqkvT, DIN, DQKV);
  wtrans_k<<<dim3(DIN / 32, 4096 / 32),  256, 0, stream>>>(Wm,   WmT,   4096, DIN);
  wtrans_k<<<dim3(DEXP / 32, DIN / 32),  256, 0, stream>>>(Wf1,  Wf1T,  DIN, DEXP);
  wtrans_k<<<dim3(DIN / 32, DEXP / 32),  256, 0, stream>>>(Wf2,  Wf2T,  DEXP, DIN);
  // ln1 + time MLP
  ln_k<<<8192, 256, 0, stream>>>(x, nullptr, ln1g, ln1b, xn);
  time_k<<<8, 256, 0, stream>>>(t, Wt1, bt1, Wt2, bt2, tp);
  // qkv GEMM (V columns written directly transposed into vt)
  gemm_bt<3><<<dim3(DQKV / 128, 8192 / 128), 256, 0, stream>>>(
      xn, DIN, WqkvT, bqkv, nullptr, qkv, DQKV, DQKV, DIN, vt);
  // two-pass differential attention
  attn_stats_k<<<1024, 256, 0, stream>>>(qkv, stm1, stl1, stm2, stl2);
  attn_pv_k<<<2048, 512, 0, stream>>>(qkv, vt, stm1, stl1, stm2, stl2, lam, aout);
  // x2 = x + attn_out @ Wm + bm
  gemm_bt<2><<<dim3(DIN / 128, 8192 / 128), 256, 0, stream>>>(
      aout, DQKV, WmT, bm, x, x2, DIN, DIN, 4096, nullptr);
  // h = LN(x2 + tp)
  ln_k<<<8192, 256, 0, stream>>>(x2, tp, lnfg, lnfb, xn);
  // ff1 = swish(h @ Wf1 + bf1)
  gemm_bt<1><<<dim3(DEXP / 128, 8192 / 128), 256, 0, stream>>>(
      xn, DIN, Wf1T, bf1, nullptr, ff1s, DEXP, DEXP, DIN, nullptr);
  // out = x2 + ff1 @ Wf2 + bf2
  gemm_bt<2><<<dim3(DIN / 128, 8192 / 128), 256, 0, stream>>>(
      ff1s, DEXP, Wf2T, bf2, x2, out, DIN, DIN, DEXP, nullptr);
}

// Round 6
// 695.587 us; speedup vs baseline: 1.1858x; 1.1858x over previous
//
#include <hip/hip_runtime.h>

// Problem dims
#define B_    8
#define N_    1024
#define DIN   512
#define H_    8
#define DH    64
#define DQKV  6144   // 2*DQ + 2*DQ + DV = 512+512+512+512+4096
#define DEXP  2048
#define DTIME 256

typedef __attribute__((ext_vector_type(8))) short s16x8;   // 8 bf16 (MFMA A/B frag)
typedef __attribute__((ext_vector_type(4))) short s16x4;
typedef __attribute__((ext_vector_type(4))) float f32x4;   // MFMA C/D frag

__device__ __forceinline__ unsigned short f2bf(float f) {
  unsigned int u = __float_as_uint(f);
  u = (u + 0x7fffu + ((u >> 16) & 1u)) >> 16;   // RNE
  return (unsigned short)u;
}

__device__ __forceinline__ void gload_lds16(const unsigned short* g, unsigned short* l) {
  __builtin_amdgcn_global_load_lds(
      (const __attribute__((address_space(1))) unsigned int*)(g),
      (__attribute__((address_space(3))) unsigned int*)(l), 16, 0, 0);
}

// ---------------- LayerNorm (D=512), optional per-batch additive row, bf16 out ----
__global__ __launch_bounds__(256) void ln_k(
    const float* __restrict__ x, const float* __restrict__ add,
    const float* __restrict__ g, const float* __restrict__ bb,
    unsigned short* __restrict__ out)
{
  int row = blockIdx.x;
  int tid = threadIdx.x;
  const float* xr = x + (size_t)row * DIN;
  float v0 = xr[tid], v1 = xr[tid + 256];
  if (add) {
    const float* ar = add + (size_t)(row >> 10) * DIN;   // row/1024 = batch idx
    v0 += ar[tid]; v1 += ar[tid + 256];
  }
  float s = v0 + v1, sq = v0 * v0 + v1 * v1;
  #pragma unroll
  for (int m = 1; m < 64; m <<= 1) { s += __shfl_xor(s, m, 64); sq += __shfl_xor(sq, m, 64); }
  __shared__ float red[8];
  int w = tid >> 6;
  if ((tid & 63) == 0) { red[w] = s; red[4 + w] = sq; }
  __syncthreads();
  s  = red[0] + red[1] + red[2] + red[3];
  sq = red[4] + red[5] + red[6] + red[7];
  float mean = s * (1.0f / DIN);
  float var  = sq * (1.0f / DIN) - mean * mean;
  float rs = rsqrtf(var + 1e-5f);
  unsigned short* orow = out + (size_t)row * DIN;
  orow[tid]       = f2bf((v0 - mean) * rs * g[tid]       + bb[tid]);
  orow[tid + 256] = f2bf((v1 - mean) * rs * g[tid + 256] + bb[tid + 256]);
}

// ---------------- f32 [R][C] -> bf16 [C][R] transpose (weights) ------------------
__global__ __launch_bounds__(256) void wtrans_k(
    const float* __restrict__ in, unsigned short* __restrict__ out, int R, int C)
{
  __shared__ float tile[32][33];
  int tx = threadIdx.x & 31, ty = threadIdx.x >> 5;
  int c0 = blockIdx.x * 32, r0 = blockIdx.y * 32;
  #pragma unroll
  for (int k = 0; k < 4; ++k)
    tile[ty + k * 8][tx] = in[(size_t)(r0 + ty + k * 8) * C + c0 + tx];
  __syncthreads();
  #pragma unroll
  for (int k = 0; k < 4; ++k)
    out[(size_t)(c0 + ty + k * 8) * R + r0 + tx] = f2bf(tile[tx][ty + k * 8]);
}

// ---------------- time MLP: tp[b][512] = swish(t@Wt1+bt1)@Wt2+bt2 ---------------
__global__ __launch_bounds__(256) void time_k(
    const float* __restrict__ t, const float* __restrict__ Wt1, const float* __restrict__ bt1,
    const float* __restrict__ Wt2, const float* __restrict__ bt2, float* __restrict__ tp)
{
  int b = blockIdx.x, tid = threadIdx.x;
  __shared__ float tl[256], hl[256];
  tl[tid] = t[(size_t)b * 256 + tid];
  __syncthreads();
  float a = bt1[tid];
  for (int k = 0; k < 256; ++k) a += tl[k] * Wt1[(size_t)k * 256 + tid];
  hl[tid] = a / (1.0f + __expf(-a));
  __syncthreads();
  for (int j = tid; j < 512; j += 256) {
    float a2 = bt2[j];
    for (int k = 0; k < 256; ++k) a2 += hl[k] * Wt2[(size_t)k * 512 + j];
    tp[(size_t)b * 512 + j] = a2;
  }
}

// ---------------- bf16 MFMA GEMM: C = epi(A @ Bt^T + bias [+res]) ---------------
// A [M][lda] bf16 ; Bt [N][K] bf16 ; 128x128 tile, BK=32, 4 waves (2x2 of 64x64)
// global_load_lds width-16 staging into linear LDS (m97 structure).
// EPI: 0 = bias -> bf16 ; 1 = bias+swish -> bf16 ; 2 = bias+res(f32) -> f32
//      3 = bias -> bf16, but V-columns (n0>=2048) written transposed into vtout
template<int EPI>
__global__ __launch_bounds__(256) void gemm_bt(
    const unsigned short* __restrict__ A, int lda,
    const unsigned short* __restrict__ Bt,
    const float* __restrict__ bias, const float* __restrict__ res,
    void* __restrict__ C, int ldc, int N, int K,
    unsigned short* __restrict__ vtout)
{
  __shared__ __attribute__((aligned(16))) unsigned short As[128 * 32];
  __shared__ __attribute__((aligned(16))) unsigned short Bs[128 * 32];
  int tid = threadIdx.x;
  int m0 = blockIdx.y * 128, n0 = blockIdx.x * 128;
  int lane = tid & 63, wid = tid >> 6;
  int wr = wid >> 1, wc = wid & 1;
  int lr = lane & 15, lg = lane >> 4, lk = lg * 8;
  f32x4 zero = {0.f, 0.f, 0.f, 0.f};
  f32x4 acc[4][4];
  #pragma unroll
  for (int i = 0; i < 4; ++i)
    #pragma unroll
    for (int j = 0; j < 4; ++j) acc[i][j] = zero;
  // staging: wave wid covers rows wid*16..wid*16+15 of each 64-row half
  int srow = wid * 16 + (lane >> 2);
  int schunk = (lane & 3) * 8;
  const unsigned short* gA0 = A  + (size_t)(m0 + srow) * lda + schunk;
  const unsigned short* gA1 = gA0 + (size_t)64 * lda;
  const unsigned short* gB0 = Bt + (size_t)(n0 + srow) * K + schunk;
  const unsigned short* gB1 = gB0 + (size_t)64 * K;
  unsigned short* lA0 = As + wid * 512;          // wave-uniform bases
  unsigned short* lA1 = As + 2048 + wid * 512;
  unsigned short* lB0 = Bs + wid * 512;
  unsigned short* lB1 = Bs + 2048 + wid * 512;
  for (int kt = 0; kt < K; kt += 32) {
    gload_lds16(gA0 + kt, lA0);
    gload_lds16(gA1 + kt, lA1);
    gload_lds16(gB0 + kt, lB0);
    gload_lds16(gB1 + kt, lB1);
    __syncthreads();
    s16x8 af[4], bf[4];
    #pragma unroll
    for (int mf = 0; mf < 4; ++mf) af[mf] = *(const s16x8*)&As[(wr * 64 + mf * 16 + lr) * 32 + lk];
    #pragma unroll
    for (int nf = 0; nf < 4; ++nf) bf[nf] = *(const s16x8*)&Bs[(wc * 64 + nf * 16 + lr) * 32 + lk];
    #pragma unroll
    for (int mf = 0; mf < 4; ++mf)
      #pragma unroll
      for (int nf = 0; nf < 4; ++nf)
        acc[mf][nf] = __builtin_amdgcn_mfma_f32_16x16x32_bf16(af[mf], bf[nf], acc[mf][nf], 0, 0, 0);
    __syncthreads();
  }
  if (EPI == 3 && n0 >= 2048) {
    // V columns -> vt [bh][c(512)][kv(1024)], packed 8B stores (4 consecutive kv)
    #pragma unroll
    for (int mf = 0; mf < 4; ++mf) {
      int row = m0 + wr * 64 + mf * 16 + lg * 4;
      int bb = row >> 10, nn = row & 1023;
      #pragma unroll
      for (int nf = 0; nf < 4; ++nf) {
        int col = n0 + wc * 64 + nf * 16 + lr;
        float bcol = bias[col];
        int hc = col - 2048;
        int hh = hc >> 9, cc = hc & 511;
        unsigned short pk[4];
        #pragma unroll
        for (int r = 0; r < 4; ++r) pk[r] = f2bf(acc[mf][nf][r] + bcol);
        *(s16x4*)(vtout + ((size_t)((bb * 8 + hh) * 512 + cc)) * 1024 + nn) = *(const s16x4*)pk;
      }
    }
    return;
  }
  #pragma unroll
  for (int mf = 0; mf < 4; ++mf)
    #pragma unroll
    for (int nf = 0; nf < 4; ++nf) {
      int col = n0 + wc * 64 + nf * 16 + lr;
      float bcol = bias[col];
      #pragma unroll
      for (int r = 0; r < 4; ++r) {
        int row = m0 + wr * 64 + mf * 16 + lg * 4 + r;
        float v = acc[mf][nf][r] + bcol;
        if (EPI == 1) v = v / (1.0f + __expf(-v));            // swish
        if (EPI == 2) {
          v += res[(size_t)row * N + col];
          ((float*)C)[(size_t)row * ldc + col] = v;
        } else {
          ((unsigned short*)C)[(size_t)row * ldc + col] = f2bf(v);
        }
      }
    }
}

// ---------------- fused differential attention, QBLK=64, exact two-pass ---------
// block = (bh, qtile of 64 rows), 8 waves: wave w -> rs=w&3 (16-row stripe),
//                                          kh=w>>2 (softmax-type / kv-half role)
// pass 1: wave (rs,kh) computes exact (m,l) for rows rs*16.. of softmax kh over
//         all 1024 kv (batched K loads, online m/l, shfl-merge, stats->LDS).
// pass 2: per 128-kv tile: wave computes S1 AND S2 for its 16 rows x its 64-kv
//         half (bit-identical MFMA order => exact), P=e1/l1-lam*e2/l2 in regs ->
//         bf16 P LDS [64][132] dbuf; ONE barrier; PV vs V-frags batch-issued at
//         loop top (latency drains under QK+exp+barrier).
__global__ __launch_bounds__(512, 2) void attn_k(
    const unsigned short* __restrict__ qkv, const unsigned short* __restrict__ vt,
    const float* __restrict__ lamp, unsigned short* __restrict__ aout /* = qkv+2048 */)
{
  const float scale = 0.125f;
  __shared__ __attribute__((aligned(16))) unsigned short P[2][64][132]; // 264B stride
  __shared__ float sm[2][64], sl[2][64];
  int w0 = blockIdx.x;
  int bx = (w0 & 7) * 128 + (w0 >> 3);        // 1024 blocks, bijective XCD swizzle
  int bh = bx >> 4, qt = bx & 15;
  int b = bh >> 3, h = bh & 7;
  int tid = threadIdx.x;
  int lane = tid & 63, w = tid >> 6;
  int rs = w & 3, kh = w >> 2;
  int lr = lane & 15, lg = lane >> 4, lk = lg * 8;
  int qc1 = h * 64, qc2 = 512 + h * 64, kc1 = 1024 + h * 64, kc2 = 1536 + h * 64;
  f32x4 zero = {0.f, 0.f, 0.f, 0.f};

  // Q fragments for rows qt*64 + rs*16 + lr, both types
  s16x8 q1f[2], q2f[2];
  {
    size_t ro = (size_t)(b * N_ + qt * 64 + rs * 16 + lr) * DQKV;
    #pragma unroll
    for (int kf = 0; kf < 2; ++kf) {
      q1f[kf] = *(const s16x8*)(qkv + ro + qc1 + kf * 32 + lk);
      q2f[kf] = *(const s16x8*)(qkv + ro + qc2 + kf * 32 + lk);
    }
  }

  // ---------------- pass 1: exact stats for (rows rs*16.., type kh) ------------
  {
    int kc = kh ? kc2 : kc1;
    s16x8 qf0 = kh ? q2f[0] : q1f[0];
    s16x8 qf1 = kh ? q2f[1] : q1f[1];
    float mp[4], lp[4];
    #pragma unroll
    for (int r = 0; r < 4; ++r) { mp[r] = -1e30f; lp[r] = 0.f; }
    for (int kt = 0; kt < 8; ++kt) {
      f32x4 s[8];
      #pragma unroll
      for (int nf = 0; nf < 8; ++nf) s[nf] = zero;
      #pragma unroll
      for (int kf = 0; kf < 2; ++kf) {
        s16x8 kb[8];
        #pragma unroll
        for (int nf = 0; nf < 8; ++nf)
          kb[nf] = *(const s16x8*)(qkv + (size_t)(b * N_ + kt * 128 + nf * 16 + lr) * DQKV
                                   + kc + kf * 32 + lk);
        s16x8 qf = kf ? qf1 : qf0;
        #pragma unroll
        for (int nf = 0; nf < 8; ++nf)
          s[nf] = __builtin_amdgcn_mfma_f32_16x16x32_bf16(qf, kb[nf], s[nf], 0, 0, 0);
      }
      #pragma unroll
      for (int r = 0; r < 4; ++r) {
        float nm = mp[r];
        #pragma unroll
        for (int nf = 0; nf < 8; ++nf) nm = fmaxf(nm, s[nf][r] * scale);
        float ps = 0.f;
        #pragma unroll
        for (int nf = 0; nf < 8; ++nf) ps += __expf(s[nf][r] * scale - nm);
        lp[r] = lp[r] * __expf(mp[r] - nm) + ps;
        mp[r] = nm;
      }
    }
    // merge across the 16 lr lanes (cols)
    #pragma unroll
    for (int r = 0; r < 4; ++r) {
      #pragma unroll
      for (int d = 1; d < 16; d <<= 1) {
        float om = __shfl_xor(mp[r], d, 64), ol = __shfl_xor(lp[r], d, 64);
        float nm = fmaxf(mp[r], om);
        lp[r] = lp[r] * __expf(mp[r] - nm) + ol * __expf(om - nm);
        mp[r] = nm;
      }
    }
    if (lr == 0) {
      #pragma unroll
      for (int r = 0; r < 4; ++r) {
        sm[kh][rs * 16 + lg * 4 + r] = mp[r];
        sl[kh][rs * 16 + lg * 4 + r] = lp[r];
      }
    }
  }
  __syncthreads();

  // per-lane normalization constants for this wave's 16-row stripe
  float lam = *lamp;
  float m1v[4], r1v[4], m2v[4], r2v[4];
  #pragma unroll
  for (int r = 0; r < 4; ++r) {
    int row = rs * 16 + lg * 4 + r;
    m1v[r] = sm[0][row]; r1v[r] = 1.f / sl[0][row];
    m2v[r] = sm[1][row]; r2v[r] = lam / sl[1][row];
  }

  // ---------------- pass 2: P tiles + PV ---------------------------------------
  f32x4 O[4][4];
  #pragma unroll
  for (int mf = 0; mf < 4; ++mf)
    #pragma unroll
    for (int nf = 0; nf < 4; ++nf) O[mf][nf] = zero;

  for (int kt = 0; kt < 8; ++kt) {
    int pb = kt & 1;
    // V fragments for this tile: issued first, drain under QK+exp+barrier
    s16x8 vf[4][4];
    #pragma unroll
    for (int nf = 0; nf < 4; ++nf)
      #pragma unroll
      for (int kq = 0; kq < 4; ++kq)
        vf[nf][kq] = *(const s16x8*)(vt + (size_t)(bh * 512 + w * 64 + nf * 16 + lr) * N_
                                     + kt * 128 + kq * 32 + lk);
    // QK both types for rows rs*16.., kv-half kh (cols kh*64 + nf*16+lr)
    f32x4 s1[4], s2[4];
    #pragma unroll
    for (int nf = 0; nf < 4; ++nf) { s1[nf] = zero; s2[nf] = zero; }
    #pragma unroll
    for (int kf = 0; kf < 2; ++kf) {
      s16x8 kb[4];
      #pragma unroll
      for (int nf = 0; nf < 4; ++nf)
        kb[nf] = *(const s16x8*)(qkv + (size_t)(b * N_ + kt * 128 + kh * 64 + nf * 16 + lr) * DQKV
                                 + kc1 + kf * 32 + lk);
      #pragma unroll
      for (int nf = 0; nf < 4; ++nf)
        s1[nf] = __builtin_amdgcn_mfma_f32_16x16x32_bf16(q1f[kf], kb[nf], s1[nf], 0, 0, 0);
    }
    #pragma unroll
    for (int kf = 0; kf < 2; ++kf) {
      s16x8 kb[4];
      #pragma unroll
      for (int nf = 0; nf < 4; ++nf)
        kb[nf] = *(const s16x8*)(qkv + (size_t)(b * N_ + kt * 128 + kh * 64 + nf * 16 + lr) * DQKV
                                 + kc2 + kf * 32 + lk);
      #pragma unroll
      for (int nf = 0; nf < 4; ++nf)
        s2[nf] = __builtin_amdgcn_mfma_f32_16x16x32_bf16(q2f[kf], kb[nf], s2[nf], 0, 0, 0);
    }
    // P stripe: rows rs*16+lg*4+r, cols kh*64+nf*16+lr
    #pragma unroll
    for (int nf = 0; nf < 4; ++nf)
      #pragma unroll
      for (int r = 0; r < 4; ++r) {
        float p = __expf(s1[nf][r] * scale - m1v[r]) * r1v[r]
                - __expf(s2[nf][r] * scale - m2v[r]) * r2v[r];
        P[pb][rs * 16 + lg * 4 + r][kh * 64 + nf * 16 + lr] = f2bf(p);
      }
    __syncthreads();
    // PV: full P tile [64][128] x this wave's V cols [128][64]
    #pragma unroll
    for (int mf = 0; mf < 4; ++mf) {
      s16x8 pf[4];
      #pragma unroll
      for (int kq = 0; kq < 4; ++kq)
        pf[kq] = *(const s16x8*)&P[pb][mf * 16 + lr][kq * 32 + lk];
      #pragma unroll
      for (int nf = 0; nf < 4; ++nf)
        #pragma unroll
        for (int kq = 0; kq < 4; ++kq)
          O[mf][nf] = __builtin_amdgcn_mfma_f32_16x16x32_bf16(pf[kq], vf[nf][kq], O[mf][nf], 0, 0, 0);
    }
  }
  // epilogue
  #pragma unroll
  for (int mf = 0; mf < 4; ++mf)
    #pragma unroll
    for (int nf = 0; nf < 4; ++nf) {
      int col = h * 512 + w * 64 + nf * 16 + lr;
      #pragma unroll
      for (int r = 0; r < 4; ++r) {
        int row = b * N_ + qt * 64 + mf * 16 + lg * 4 + r;
        aout[(size_t)row * DQKV + col] = f2bf(O[mf][nf][r]);
      }
    }
}

// ---------------------------------- launcher ------------------------------------
extern "C" void kernel_launch(void* const* d_in, const int* in_sizes, int n_in,
                              void* d_out, int out_size, void* d_ws, size_t ws_size,
                              hipStream_t stream) {
  const float* x    = (const float*)d_in[0];
  const float* t    = (const float*)d_in[1];
  const float* ln1g = (const float*)d_in[2];
  const float* ln1b = (const float*)d_in[3];
  const float* Wqkv = (const float*)d_in[4];
  const float* bqkv = (const float*)d_in[5];
  const float* lam  = (const float*)d_in[6];
  const float* Wm   = (const float*)d_in[7];
  const float* bm   = (const float*)d_in[8];
  const float* Wt1  = (const float*)d_in[9];
  const float* bt1  = (const float*)d_in[10];
  const float* Wt2  = (const float*)d_in[11];
  const float* bt2  = (const float*)d_in[12];
  const float* lnfg = (const float*)d_in[13];
  const float* lnfb = (const float*)d_in[14];
  const float* Wf1  = (const float*)d_in[15];
  const float* bf1  = (const float*)d_in[16];
  const float* Wf2  = (const float*)d_in[17];
  const float* bf2  = (const float*)d_in[18];
  float* out = (float*)d_out;
  char* ws = (char*)d_ws;

  // workspace layout (bytes), ~209 MB total
  unsigned short* qkv   = (unsigned short*)(ws);                  // [8192][6144] bf16 (100.7MB)
  unsigned short* vt    = (unsigned short*)(ws + 100663296ull);   // [64][512][1024] bf16 (67MB)
  float*          x2    = (float*)(ws + 167772160ull);            // [8192][512] f32 (16.8MB)
  unsigned short* xn    = (unsigned short*)(ws + 184549376ull);   // [8192][512] bf16 (xn, then h)
  unsigned short* WqkvT = (unsigned short*)(ws + 193986560ull);   // [6144][512]
  unsigned short* WmT   = (unsigned short*)(ws + 200278016ull);   // [512][4096]
  unsigned short* Wf1T  = (unsigned short*)(ws + 204472320ull);   // [2048][512]
  unsigned short* Wf2T  = (unsigned short*)(ws + 206569472ull);   // [512][2048]
  float*          tp    = (float*)(ws + 208666624ull);            // [8][512]
  unsigned short* ff1s  = qkv;          // alias: qkv dead after attention
  unsigned short* aout  = qkv + 2048;   // alias: attention out over dead V region

  // weights -> bf16 transposed [N][K]
  wtrans_k<<<dim3(DQKV / 32, DIN / 32),  256, 0, stream>>>(Wqkv, WqkvT, DIN, DQKV);
  wtrans_k<<<dim3(DIN / 32, 4096 / 32),  256, 0, stream>>>(Wm,   WmT,   4096, DIN);
  wtrans_k<<<dim3(DEXP / 32, DIN / 32),  256, 0, stream>>>(Wf1,  Wf1T,  DIN, DEXP);
  wtrans_k<<<dim3(DIN / 32, DEXP / 32),  256, 0, stream>>>(Wf2,  Wf2T,  DEXP, DIN);
  // ln1 + time MLP
  ln_k<<<8192, 256, 0, stream>>>(x, nullptr, ln1g, ln1b, xn);
  time_k<<<8, 256, 0, stream>>>(t, Wt1, bt1, Wt2, bt2, tp);
  // qkv GEMM (V columns written directly transposed into vt)
  gemm_bt<3><<<dim3(DQKV / 128, 8192 / 128), 256, 0, stream>>>(
      xn, DIN, WqkvT, bqkv, nullptr, qkv, DQKV, DQKV, DIN, vt);
  // fused two-pass differential attention
  attn_k<<<1024, 512, 0, stream>>>(qkv, vt, lam, aout);
  // x2 = x + attn_out @ Wm + bm
  gemm_bt<2><<<dim3(DIN / 128, 8192 / 128), 256, 0, stream>>>(
      aout, DQKV, WmT, bm, x, x2, DIN, DIN, 4096, nullptr);
  // h = LN(x2 + tp)
  ln_k<<<8192, 256, 0, stream>>>(x2, tp, lnfg, lnfb, xn);
  // ff1 = swish(h @ Wf1 + bf1)
  gemm_bt<1><<<dim3(DEXP / 128, 8192 / 128), 256, 0, stream>>>(
      xn, DIN, Wf1T, bf1, nullptr, ff1s, DEXP, DEXP, DIN, nullptr);
  // out = x2 + ff1 @ Wf2 + bf2
  gemm_bt<2><<<dim3(DIN / 128, 8192 / 128), 256, 0, stream>>>(
      ff1s, DEXP, Wf2T, bf2, x2, out, DIN, DIN, DEXP, nullptr);
}

// Round 7
// 670.317 us; speedup vs baseline: 1.2305x; 1.0377x over previous
//
#include <hip/hip_runtime.h>

// Problem dims
#define B_    8
#define N_    1024
#define DIN   512
#define H_    8
#define DH    64
#define DQKV  6144   // 2*DQ + 2*DQ + DV = 512+512+512+512+4096
#define DEXP  2048
#define DTIME 256

typedef __attribute__((ext_vector_type(8))) short s16x8;   // 8 bf16 (MFMA A/B frag)
typedef __attribute__((ext_vector_type(4))) short s16x4;
typedef __attribute__((ext_vector_type(4))) float f32x4;   // MFMA C/D frag

__device__ __forceinline__ unsigned short f2bf(float f) {
  unsigned int u = __float_as_uint(f);
  u = (u + 0x7fffu + ((u >> 16) & 1u)) >> 16;   // RNE
  return (unsigned short)u;
}

__device__ __forceinline__ void gload_lds16(const unsigned short* g, unsigned short* l) {
  __builtin_amdgcn_global_load_lds(
      (const __attribute__((address_space(1))) unsigned int*)(g),
      (__attribute__((address_space(3))) unsigned int*)(l), 16, 0, 0);
}

// ---------------- LayerNorm (D=512), optional per-batch additive row, bf16 out ----
__global__ __launch_bounds__(256) void ln_k(
    const float* __restrict__ x, const float* __restrict__ add,
    const float* __restrict__ g, const float* __restrict__ bb,
    unsigned short* __restrict__ out)
{
  int row = blockIdx.x;
  int tid = threadIdx.x;
  const float* xr = x + (size_t)row * DIN;
  float v0 = xr[tid], v1 = xr[tid + 256];
  if (add) {
    const float* ar = add + (size_t)(row >> 10) * DIN;   // row/1024 = batch idx
    v0 += ar[tid]; v1 += ar[tid + 256];
  }
  float s = v0 + v1, sq = v0 * v0 + v1 * v1;
  #pragma unroll
  for (int m = 1; m < 64; m <<= 1) { s += __shfl_xor(s, m, 64); sq += __shfl_xor(sq, m, 64); }
  __shared__ float red[8];
  int w = tid >> 6;
  if ((tid & 63) == 0) { red[w] = s; red[4 + w] = sq; }
  __syncthreads();
  s  = red[0] + red[1] + red[2] + red[3];
  sq = red[4] + red[5] + red[6] + red[7];
  float mean = s * (1.0f / DIN);
  float var  = sq * (1.0f / DIN) - mean * mean;
  float rs = rsqrtf(var + 1e-5f);
  unsigned short* orow = out + (size_t)row * DIN;
  orow[tid]       = f2bf((v0 - mean) * rs * g[tid]       + bb[tid]);
  orow[tid + 256] = f2bf((v1 - mean) * rs * g[tid + 256] + bb[tid + 256]);
}

// ---------------- f32 [R][C] -> bf16 [C][R] transpose (weights) ------------------
__global__ __launch_bounds__(256) void wtrans_k(
    const float* __restrict__ in, unsigned short* __restrict__ out, int R, int C)
{
  __shared__ float tile[32][33];
  int tx = threadIdx.x & 31, ty = threadIdx.x >> 5;
  int c0 = blockIdx.x * 32, r0 = blockIdx.y * 32;
  #pragma unroll
  for (int k = 0; k < 4; ++k)
    tile[ty + k * 8][tx] = in[(size_t)(r0 + ty + k * 8) * C + c0 + tx];
  __syncthreads();
  #pragma unroll
  for (int k = 0; k < 4; ++k)
    out[(size_t)(c0 + ty + k * 8) * R + r0 + tx] = f2bf(tile[tx][ty + k * 8]);
}

// ---------------- time MLP: tp[b][512] = swish(t@Wt1+bt1)@Wt2+bt2 ---------------
__global__ __launch_bounds__(256) void time_k(
    const float* __restrict__ t, const float* __restrict__ Wt1, const float* __restrict__ bt1,
    const float* __restrict__ Wt2, const float* __restrict__ bt2, float* __restrict__ tp)
{
  int b = blockIdx.x, tid = threadIdx.x;
  __shared__ float tl[256], hl[256];
  tl[tid] = t[(size_t)b * 256 + tid];
  __syncthreads();
  float a = bt1[tid];
  for (int k = 0; k < 256; ++k) a += tl[k] * Wt1[(size_t)k * 256 + tid];
  hl[tid] = a / (1.0f + __expf(-a));
  __syncthreads();
  for (int j = tid; j < 512; j += 256) {
    float a2 = bt2[j];
    for (int k = 0; k < 256; ++k) a2 += hl[k] * Wt2[(size_t)k * 512 + j];
    tp[(size_t)b * 512 + j] = a2;
  }
}

// ---------------- bf16 MFMA GEMM: C = epi(A @ Bt^T + bias [+res]) ---------------
// A [M][lda] bf16 ; Bt [N][K] bf16 ; 128x128 tile, BK=32, 4 waves (2x2 of 64x64)
// global_load_lds width-16 staging into linear LDS (m97 structure).
// EPI: 0 = bias -> bf16 ; 1 = bias+swish -> bf16 ; 2 = bias+res(f32) -> f32
//      3 = bias -> bf16, but V-columns (n0>=2048) written transposed into vtout
template<int EPI>
__global__ __launch_bounds__(256) void gemm_bt(
    const unsigned short* __restrict__ A, int lda,
    const unsigned short* __restrict__ Bt,
    const float* __restrict__ bias, const float* __restrict__ res,
    void* __restrict__ C, int ldc, int N, int K,
    unsigned short* __restrict__ vtout)
{
  __shared__ __attribute__((aligned(16))) unsigned short As[128 * 32];
  __shared__ __attribute__((aligned(16))) unsigned short Bs[128 * 32];
  int tid = threadIdx.x;
  int m0 = blockIdx.y * 128, n0 = blockIdx.x * 128;
  int lane = tid & 63, wid = tid >> 6;
  int wr = wid >> 1, wc = wid & 1;
  int lr = lane & 15, lg = lane >> 4, lk = lg * 8;
  f32x4 zero = {0.f, 0.f, 0.f, 0.f};
  f32x4 acc[4][4];
  #pragma unroll
  for (int i = 0; i < 4; ++i)
    #pragma unroll
    for (int j = 0; j < 4; ++j) acc[i][j] = zero;
  // staging: wave wid covers rows wid*16..wid*16+15 of each 64-row half
  int srow = wid * 16 + (lane >> 2);
  int schunk = (lane & 3) * 8;
  const unsigned short* gA0 = A  + (size_t)(m0 + srow) * lda + schunk;
  const unsigned short* gA1 = gA0 + (size_t)64 * lda;
  const unsigned short* gB0 = Bt + (size_t)(n0 + srow) * K + schunk;
  const unsigned short* gB1 = gB0 + (size_t)64 * K;
  unsigned short* lA0 = As + wid * 512;          // wave-uniform bases
  unsigned short* lA1 = As + 2048 + wid * 512;
  unsigned short* lB0 = Bs + wid * 512;
  unsigned short* lB1 = Bs + 2048 + wid * 512;
  for (int kt = 0; kt < K; kt += 32) {
    gload_lds16(gA0 + kt, lA0);
    gload_lds16(gA1 + kt, lA1);
    gload_lds16(gB0 + kt, lB0);
    gload_lds16(gB1 + kt, lB1);
    __syncthreads();
    s16x8 af[4], bf[4];
    #pragma unroll
    for (int mf = 0; mf < 4; ++mf) af[mf] = *(const s16x8*)&As[(wr * 64 + mf * 16 + lr) * 32 + lk];
    #pragma unroll
    for (int nf = 0; nf < 4; ++nf) bf[nf] = *(const s16x8*)&Bs[(wc * 64 + nf * 16 + lr) * 32 + lk];
    #pragma unroll
    for (int mf = 0; mf < 4; ++mf)
      #pragma unroll
      for (int nf = 0; nf < 4; ++nf)
        acc[mf][nf] = __builtin_amdgcn_mfma_f32_16x16x32_bf16(af[mf], bf[nf], acc[mf][nf], 0, 0, 0);
    __syncthreads();
  }
  if (EPI == 3 && n0 >= 2048) {
    // V columns -> vt [bh][c(512)][kv(1024)], packed 8B stores (4 consecutive kv)
    #pragma unroll
    for (int mf = 0; mf < 4; ++mf) {
      int row = m0 + wr * 64 + mf * 16 + lg * 4;
      int bb = row >> 10, nn = row & 1023;
      #pragma unroll
      for (int nf = 0; nf < 4; ++nf) {
        int col = n0 + wc * 64 + nf * 16 + lr;
        float bcol = bias[col];
        int hc = col - 2048;
        int hh = hc >> 9, cc = hc & 511;
        unsigned short pk[4];
        #pragma unroll
        for (int r = 0; r < 4; ++r) pk[r] = f2bf(acc[mf][nf][r] + bcol);
        *(s16x4*)(vtout + ((size_t)((bb * 8 + hh) * 512 + cc)) * 1024 + nn) = *(const s16x4*)pk;
      }
    }
    return;
  }
  #pragma unroll
  for (int mf = 0; mf < 4; ++mf)
    #pragma unroll
    for (int nf = 0; nf < 4; ++nf) {
      int col = n0 + wc * 64 + nf * 16 + lr;
      float bcol = bias[col];
      #pragma unroll
      for (int r = 0; r < 4; ++r) {
        int row = m0 + wr * 64 + mf * 16 + lg * 4 + r;
        float v = acc[mf][nf][r] + bcol;
        if (EPI == 1) v = v / (1.0f + __expf(-v));            // swish
        if (EPI == 2) {
          v += res[(size_t)row * N + col];
          ((float*)C)[(size_t)row * ldc + col] = v;
        } else {
          ((unsigned short*)C)[(size_t)row * ldc + col] = f2bf(v);
        }
      }
    }
}

// ---------------- fused differential attention, QBLK=64, LDS-staged K -----------
// block = (bh, qtile of 64 rows), 8 waves: rs=w&3 (16-row q-stripe), kh=w>>2.
// K staged per 64-kv tile into LDS via global_load_lds (both types, 128 cols),
// XOR-swizzled (pre-swizzled global source + swizzled ds_read, G4/rule21).
// No-max softmax (scores bounded; e^S exact in f32) => pass1 is pure sum-exp.
// pass1: wave (rs,kh) accumulates l for its 16 rows x type kh over all kv
//        (K double-buffered, stage issued at loop top, 1 barrier/iter).
// pass2: wave computes S1+S2 for its rows x kv-half kh, P=e1/l1-lam*e2/l2 ->
//        bf16 P LDS (dbuf); V prefetched to regs before the P-barrier (drained
//        by it); K restaged right after the barrier so it drains under PV.
__global__ __launch_bounds__(512, 2) void attn_k(
    const unsigned short* __restrict__ qkv, const unsigned short* __restrict__ vt,
    const float* __restrict__ lamp, unsigned short* __restrict__ aout /* = qkv+2048 */)
{
  const float scale = 0.125f;
  // KP: pass1 = Kd[2][64][128] (16384 u16); pass2 = Ks[64][128] + P[2][64][68] (16896 u16)
  __shared__ __attribute__((aligned(16))) unsigned short KP[16896];
  __shared__ float sl[2][64];
  int w0 = blockIdx.x;
  int bx = (w0 & 7) * 128 + (w0 >> 3);        // 1024 blocks, bijective XCD swizzle
  int bh = bx >> 4, qt = bx & 15;
  int b = bh >> 3, h = bh & 7;
  int tid = threadIdx.x;
  int lane = tid & 63, w = tid >> 6;
  int rs = w & 3, kh = w >> 2;
  int lr = lane & 15, lg = lane >> 4, lk = lg * 8;
  int qc1 = h * 64, qc2 = 512 + h * 64, kc1 = 1024 + h * 64, kc2 = 1536 + h * 64;
  f32x4 zero = {0.f, 0.f, 0.f, 0.f};
  const unsigned short* kvbase = qkv + (size_t)(b * N_) * DQKV;

  // staging source swizzle: lane covers row w*8 + i*4 + (lane>>4), 16B chunk
  // colidx = (lane&15) ^ (row&7); row&7 = (lane>>4) for i=0, 4+(lane>>4) for i=1
  int srw = lane >> 4;                        // 0..3
  int ci0 = (lane & 15) ^ srw;
  int ci1 = (lane & 15) ^ (4 + srw);
  int scol0 = (ci0 < 8) ? (kc1 + ci0 * 8) : (kc2 + (ci0 - 8) * 8);
  int scol1 = (ci1 < 8) ? (kc1 + ci1 * 8) : (kc2 + (ci1 - 8) * 8);

  // Q fragments (both types) for rows qt*64 + rs*16 + lr
  s16x8 q1f[2], q2f[2];
  {
    size_t ro = (size_t)(b * N_ + qt * 64 + rs * 16 + lr) * DQKV;
    q1f[0] = *(const s16x8*)(qkv + ro + qc1 + lk);
    q1f[1] = *(const s16x8*)(qkv + ro + qc1 + 32 + lk);
    q2f[0] = *(const s16x8*)(qkv + ro + qc2 + lk);
    q2f[1] = *(const s16x8*)(qkv + ro + qc2 + 32 + lk);
  }

#define STAGE_K(Lb, kt)                                                              \
  do {                                                                               \
    gload_lds16(kvbase + (size_t)((kt) * 64 + w * 8 + srw) * DQKV + scol0,           \
                (Lb) + (w * 8) * 128);                                               \
    gload_lds16(kvbase + (size_t)((kt) * 64 + w * 8 + 4 + srw) * DQKV + scol1,       \
                (Lb) + (w * 8 + 4) * 128);                                           \
  } while (0)

#define KREAD(Lb, row, colu) (*(const s16x8*)&(Lb)[(row) * 128 + ((colu) ^ (((row) & 7) * 8))])

  // ---------------- pass 1: l (sum of exp) for (rows rs*16.., type kh) ----------
  {
    unsigned short* K0 = KP;
    unsigned short* K1 = KP + 8192;
    s16x8 qa = kh ? q2f[0] : q1f[0];
    s16x8 qb = kh ? q2f[1] : q1f[1];
    int tco = kh ? 64 : 0;
    float lp[4] = {0.f, 0.f, 0.f, 0.f};
    STAGE_K(K0, 0);
    __syncthreads();
    for (int kt = 0; kt < 16; ++kt) {
      unsigned short* Lb = (kt & 1) ? K1 : K0;
      if (kt < 15) STAGE_K((kt & 1) ? K0 : K1, kt + 1);   // other buffer: race-free
      f32x4 s[4];
      #pragma unroll
      for (int nf = 0; nf < 4; ++nf) {
        int row = nf * 16 + lr;
        s16x8 kb0 = KREAD(Lb, row, tco + lk);
        s16x8 kb1 = KREAD(Lb, row, tco + 32 + lk);
        f32x4 acc = __builtin_amdgcn_mfma_f32_16x16x32_bf16(qa, kb0, zero, 0, 0, 0);
        s[nf] = __builtin_amdgcn_mfma_f32_16x16x32_bf16(qb, kb1, acc, 0, 0, 0);
      }
      #pragma unroll
      for (int nf = 0; nf < 4; ++nf)
        #pragma unroll
        for (int r = 0; r < 4; ++r)
          lp[r] += __expf(s[nf][r] * scale);
      __syncthreads();                 // next-tile stage drained; all reads done
    }
    #pragma unroll
    for (int r = 0; r < 4; ++r)
      #pragma unroll
      for (int d = 1; d < 16; d <<= 1) lp[r] += __shfl_xor(lp[r], d, 64);
    if (lr == 0)
      #pragma unroll
      for (int r = 0; r < 4; ++r) sl[kh][rs * 16 + lg * 4 + r] = lp[r];
    __syncthreads();
  }

  // normalizers for this lane's q-rows
  float lam = *lamp;
  float r1v[4], r2v[4];
  #pragma unroll
  for (int r = 0; r < 4; ++r) {
    int row = rs * 16 + lg * 4 + r;
    r1v[r] = 1.f / sl[0][row];
    r2v[r] = lam / sl[1][row];
  }

  // ---------------- pass 2: P tiles + PV ---------------------------------------
  unsigned short* Ks = KP;
  unsigned short* Pb = KP + 8192;
  f32x4 O[4][4];
  #pragma unroll
  for (int mf = 0; mf < 4; ++mf)
    #pragma unroll
    for (int nf = 0; nf < 4; ++nf) O[mf][nf] = zero;
  STAGE_K(Ks, 0);
  __syncthreads();
  for (int kt = 0; kt < 16; ++kt) {
    unsigned short* Pt = Pb + (kt & 1) * 4352;
    // QK both types, kv rows kh*32 + nf*16 + lr (bit-identical order to pass 1)
    f32x4 s1[2], s2[2];
    #pragma unroll
    for (int nf = 0; nf < 2; ++nf) {
      int row = kh * 32 + nf * 16 + lr;
      s16x8 a0 = KREAD(Ks, row, lk);
      s16x8 a1 = KREAD(Ks, row, 32 + lk);
      s16x8 b0 = KREAD(Ks, row, 64 + lk);
      s16x8 b1 = KREAD(Ks, row, 96 + lk);
      f32x4 t1 = __builtin_amdgcn_mfma_f32_16x16x32_bf16(q1f[0], a0, zero, 0, 0, 0);
      s1[nf]   = __builtin_amdgcn_mfma_f32_16x16x32_bf16(q1f[1], a1, t1, 0, 0, 0);
      f32x4 t2 = __builtin_amdgcn_mfma_f32_16x16x32_bf16(q2f[0], b0, zero, 0, 0, 0);
      s2[nf]   = __builtin_amdgcn_mfma_f32_16x16x32_bf16(q2f[1], b1, t2, 0, 0, 0);
    }
    // V prefetch: issued before the barrier, drained by it -> ready for PV
    s16x8 vf[4][2];
    #pragma unroll
    for (int nf = 0; nf < 4; ++nf)
      #pragma unroll
      for (int kq = 0; kq < 2; ++kq)
        vf[nf][kq] = *(const s16x8*)(vt + (size_t)(bh * 512 + w * 64 + nf * 16 + lr) * N_
                                     + kt * 64 + kq * 32 + lk);
    // P = e1/l1 - lam*e2/l2 (no-max exact softmax), write stripe
    #pragma unroll
    for (int nf = 0; nf < 2; ++nf)
      #pragma unroll
      for (int r = 0; r < 4; ++r) {
        float p = __expf(s1[nf][r] * scale) * r1v[r]
                - __expf(s2[nf][r] * scale) * r2v[r];
        Pt[(rs * 16 + lg * 4 + r) * 68 + kh * 32 + nf * 16 + lr] = f2bf(p);
      }
    __syncthreads();                   // P ready; K consumed by all; vf landed
    if (kt < 15) STAGE_K(Ks, kt + 1);  // safe: all K reads done; drains under PV
    // PV: full P tile [64][64] x wave's 64 v-channels
    #pragma unroll
    for (int mf = 0; mf < 4; ++mf) {
      s16x8 pf0 = *(const s16x8*)&Pt[(mf * 16 + lr) * 68 + lk];
      s16x8 pf1 = *(const s16x8*)&Pt[(mf * 16 + lr) * 68 + 32 + lk];
      #pragma unroll
      for (int nf = 0; nf < 4; ++nf) {
        O[mf][nf] = __builtin_amdgcn_mfma_f32_16x16x32_bf16(pf0, vf[nf][0], O[mf][nf], 0, 0, 0);
        O[mf][nf] = __builtin_amdgcn_mfma_f32_16x16x32_bf16(pf1, vf[nf][1], O[mf][nf], 0, 0, 0);
      }
    }
    __syncthreads();                   // stage(kt+1) drained; P reads done
  }
#undef STAGE_K
#undef KREAD
  // epilogue
  #pragma unroll
  for (int mf = 0; mf < 4; ++mf)
    #pragma unroll
    for (int nf = 0; nf < 4; ++nf) {
      int col = h * 512 + w * 64 + nf * 16 + lr;
      #pragma unroll
      for (int r = 0; r < 4; ++r) {
        int row = b * N_ + qt * 64 + mf * 16 + lg * 4 + r;
        aout[(size_t)row * DQKV + col] = f2bf(O[mf][nf][r]);
      }
    }
}

// ---------------------------------- launcher ------------------------------------
extern "C" void kernel_launch(void* const* d_in, const int* in_sizes, int n_in,
                              void* d_out, int out_size, void* d_ws, size_t ws_size,
                              hipStream_t stream) {
  const float* x    = (const float*)d_in[0];
  const float* t    = (const float*)d_in[1];
  const float* ln1g = (const float*)d_in[2];
  const float* ln1b = (const float*)d_in[3];
  const float* Wqkv = (const float*)d_in[4];
  const float* bqkv = (const float*)d_in[5];
  const float* lam  = (const float*)d_in[6];
  const float* Wm   = (const float*)d_in[7];
  const float* bm   = (const float*)d_in[8];
  const float* Wt1  = (const float*)d_in[9];
  const float* bt1  = (const float*)d_in[10];
  const float* Wt2  = (const float*)d_in[11];
  const float* bt2  = (const float*)d_in[12];
  const float* lnfg = (const float*)d_in[13];
  const float* lnfb = (const float*)d_in[14];
  const float* Wf1  = (const float*)d_in[15];
  const float* bf1  = (const float*)d_in[16];
  const float* Wf2  = (const float*)d_in[17];
  const float* bf2  = (const float*)d_in[18];
  float* out = (float*)d_out;
  char* ws = (char*)d_ws;

  // workspace layout (bytes), ~209 MB total
  unsigned short* qkv   = (unsigned short*)(ws);                  // [8192][6144] bf16 (100.7MB)
  unsigned short* vt    = (unsigned short*)(ws + 100663296ull);   // [64][512][1024] bf16 (67MB)
  float*          x2    = (float*)(ws + 167772160ull);            // [8192][512] f32 (16.8MB)
  unsigned short* xn    = (unsigned short*)(ws + 184549376ull);   // [8192][512] bf16 (xn, then h)
  unsigned short* WqkvT = (unsigned short*)(ws + 193986560ull);   // [6144][512]
  unsigned short* WmT   = (unsigned short*)(ws + 200278016ull);   // [512][4096]
  unsigned short* Wf1T  = (unsigned short*)(ws + 204472320ull);   // [2048][512]
  unsigned short* Wf2T  = (unsigned short*)(ws + 206569472ull);   // [512][2048]
  float*          tp    = (float*)(ws + 208666624ull);            // [8][512]
  unsigned short* ff1s  = qkv;          // alias: qkv dead after attention
  unsigned short* aout  = qkv + 2048;   // alias: attention out over dead V region

  // weights -> bf16 transposed [N][K]
  wtrans_k<<<dim3(DQKV / 32, DIN / 32),  256, 0, stream>>>(Wqkv, WqkvT, DIN, DQKV);
  wtrans_k<<<dim3(DIN / 32, 4096 / 32),  256, 0, stream>>>(Wm,   WmT,   4096, DIN);
  wtrans_k<<<dim3(DEXP / 32, DIN / 32),  256, 0, stream>>>(Wf1,  Wf1T,  DIN, DEXP);
  wtrans_k<<<dim3(DIN / 32, DEXP / 32),  256, 0, stream>>>(Wf2,  Wf2T,  DEXP, DIN);
  // ln1 + time MLP
  ln_k<<<8192, 256, 0, stream>>>(x, nullptr, ln1g, ln1b, xn);
  time_k<<<8, 256, 0, stream>>>(t, Wt1, bt1, Wt2, bt2, tp);
  // qkv GEMM (V columns written directly transposed into vt)
  gemm_bt<3><<<dim3(DQKV / 128, 8192 / 128), 256, 0, stream>>>(
      xn, DIN, WqkvT, bqkv, nullptr, qkv, DQKV, DQKV, DIN, vt);
  // fused two-pass differential attention (LDS-staged K, no-max softmax)
  attn_k<<<1024, 512, 0, stream>>>(qkv, vt, lam, aout);
  // x2 = x + attn_out @ Wm + bm
  gemm_bt<2><<<dim3(DIN / 128, 8192 / 128), 256, 0, stream>>>(
      aout, DQKV, WmT, bm, x, x2, DIN, DIN, 4096, nullptr);
  // h = LN(x2 + tp)
  ln_k<<<8192, 256, 0, stream>>>(x2, tp, lnfg, lnfb, xn);
  // ff1 = swish(h @ Wf1 + bf1)
  gemm_bt<1><<<dim3(DEXP / 128, 8192 / 128), 256, 0, stream>>>(
      xn, DIN, Wf1T, bf1, nullptr, ff1s, DEXP, DEXP, DIN, nullptr);
  // out = x2 + ff1 @ Wf2 + bf2
  gemm_bt<2><<<dim3(DIN / 128, 8192 / 128), 256, 0, stream>>>(
      ff1s, DEXP, Wf2T, bf2, x2, out, DIN, DIN, DEXP, nullptr);
}